// Round 1
// baseline (313.435 us; speedup 1.0000x reference)
//
#include <hip/hip_runtime.h>
#include <math.h>

#define NCONF  64
#define NATOMS 256
#define NCOEFF 45
#define NAOV   12
#define NPAIR  66
#define NZ     8
#define NA     8
#define RAD    384    // 12 * 32
#define ANG    4224   // 66 * 64
#define TOT    4608
#define ATOMS_PER_BLOCK 4

// triu_indices(12, k=1), i-major order
__constant__ unsigned char c_iu[NPAIR] = {
    0,0,0,0,0,0,0,0,0,0,0,
    1,1,1,1,1,1,1,1,1,1,
    2,2,2,2,2,2,2,2,2,
    3,3,3,3,3,3,3,3,
    4,4,4,4,4,4,4,
    5,5,5,5,5,5,
    6,6,6,6,6,
    7,7,7,7,
    8,8,8,
    9,9,
    10
};
__constant__ unsigned char c_ju[NPAIR] = {
    1,2,3,4,5,6,7,8,9,10,11,
    2,3,4,5,6,7,8,9,10,11,
    3,4,5,6,7,8,9,10,11,
    4,5,6,7,8,9,10,11,
    5,6,7,8,9,10,11,
    6,7,8,9,10,11,
    7,8,9,10,11,
    8,9,10,11,
    9,10,11,
    10,11,
    11
};

// linspace(0.5, 3.5, 16)  (shfS == shfR: same bounds, same eta=16)
__constant__ float c_shfS[16] = {
    0.5f, 0.7f, 0.9f, 1.1f, 1.3f, 1.5f, 1.7f, 1.9f,
    2.1f, 2.3f, 2.5f, 2.7f, 2.9f, 3.1f, 3.3f, 3.5f
};
// linspace(0.5, 3.5, 8)
__constant__ float c_shfA[8] = {
    0.5f, 0.92857142857f, 1.35714285714f, 1.78571428571f,
    2.21428571429f, 2.64285714286f, 3.07142857143f, 3.5f
};
// cos/sin of shfZ = pi/16 + k*pi/8 (k=0..7); matches linspace(0.19634954, 2.94524311, 8)
__constant__ float c_cosZ[8] = {
     0.98078528f,  0.83146961f,  0.55557023f,  0.19509032f,
    -0.19509032f, -0.55557023f, -0.83146961f, -0.98078528f
};
__constant__ float c_sinZ[8] = {
    0.19509032f, 0.55557023f, 0.83146961f, 0.98078528f,
    0.98078528f, 0.83146961f, 0.55557023f, 0.19509032f
};

// Within-wave LDS write->read ordering. Does NOT drain vmcnt, so global
// stores stay in flight across the fence (unlike __syncthreads).
// Wave is lockstep; DS ops issue in program order; lgkmcnt(0) makes all
// prior LDS writes visible to all lanes of this wave.
#define WAVE_FENCE() asm volatile("s_waitcnt lgkmcnt(0)" ::: "memory")

// d-block column permutation [0,2,5,4,3,1]: h=0 -> cols {0,2,5}, h=1 -> cols {4,3,1}

__global__ __launch_bounds__(256)
void OrbitalAEVComputer_40492951667225_kernel(const float* __restrict__ coef,
                                              float* __restrict__ out) {
    // Per-wave LDS slices; 4 waves per block, one atom per wave, NO block barriers.
    __shared__ __align__(16) float s_f1[ATOMS_PER_BLOCK][NPAIR * NZ];  // 8448 B
    __shared__ __align__(16) float s_f2[ATOMS_PER_BLOCK][NPAIR * NA];  // 8448 B
    __shared__ float s_dist[ATOMS_PER_BLOCK][NAOV];                    //  192 B
    __shared__ float s_nv[ATOMS_PER_BLOCK][NAOV][3];                   //  576 B
    __shared__ float s_c95[ATOMS_PER_BLOCK][NPAIR];                    // 1056 B
    __shared__ float s_avd[ATOMS_PER_BLOCK][NPAIR];                    // 1056 B
    // total 19776 B/block -> 8 blocks/CU within the 160 KiB LDS budget

    const int t = threadIdx.x;
    const int w = t >> 6;        // wave id = which atom of this block
    const int l = t & 63;        // lane within wave
    const int atom = blockIdx.x * ATOMS_PER_BLOCK + w;
    const float* c = coef + (size_t)atom * NCOEFF;
    float* o = out + (size_t)atom * TOT;

    // ---- phase A: build the 12 AOV vectors (lanes 0-11) ----
    if (l < NAOV) {
        float x, y, z;
        if (l < 4) {
            x = c[9 + 3 * l]; y = c[10 + 3 * l]; z = c[11 + 3 * l];
        } else {
            int r = (l - 4) >> 1, h = (l - 4) & 1;
            const int base = 21 + 6 * r;
            if (h == 0) { x = c[base + 0]; y = c[base + 2]; z = c[base + 5]; }
            else        { x = c[base + 4]; y = c[base + 3]; z = c[base + 1]; }
        }
        float d = sqrtf(x * x + y * y + z * z);
        bool zm = (fabsf(x) < 1e-12f) && (fabsf(y) < 1e-12f) && (fabsf(z) < 1e-12f);
        float inv = zm ? 0.0f : 1.0f / d;   // if not masked, d >= 1e-12 -> finite
        s_dist[w][l] = d;
        s_nv[w][l][0] = x * inv;
        s_nv[w][l][1] = y * inv;
        s_nv[w][l][2] = z * inv;
    }
    WAVE_FENCE();

    // ---- phase B (early!): radial stores — need only dist, start HBM writes now ----
    for (int i4 = l; i4 < RAD / 4; i4 += 64) {
        int e = i4 * 4;           // element 0..383
        int p = e >> 5;           // AOV index
        float d = s_dist[w][p];
        int k0 = e & 31;          // 4-aligned, never crosses the 16-boundary
        float4 v;
        float df;
        df = d - c_shfS[(k0 + 0) & 15]; v.x = __expf(-16.0f * df * df);
        df = d - c_shfS[(k0 + 1) & 15]; v.y = __expf(-16.0f * df * df);
        df = d - c_shfS[(k0 + 2) & 15]; v.z = __expf(-16.0f * df * df);
        df = d - c_shfS[(k0 + 3) & 15]; v.w = __expf(-16.0f * df * df);
        reinterpret_cast<float4*>(o)[i4] = v;
    }

    // ---- phase C: per-pair cos / avg-dist (66 pairs over 64 lanes) ----
    for (int p = l; p < NPAIR; p += 64) {
        int i = c_iu[p], j = c_ju[p];
        float cang = s_nv[w][i][0] * s_nv[w][j][0]
                   + s_nv[w][i][1] * s_nv[w][j][1]
                   + s_nv[w][i][2] * s_nv[w][j][2];
        s_c95[w][p] = 0.95f * cang;              // cos(angle)
        s_avd[w][p] = 0.5f * (s_dist[w][i] + s_dist[w][j]);
    }
    WAVE_FENCE();

    // ---- phase D: f1[q][z] and f2[q][a] (528 values each) ----
    for (int idx = l; idx < NPAIR * NZ; idx += 64) {
        int q = idx >> 3, k = idx & 7;
        float c95 = s_c95[w][q];
        float sinv = sqrtf(fmaxf(1.0f - c95 * c95, 0.0f));  // sin(angle) >= 0
        // cos(angle - shfZ) = cos(angle)cos(shfZ) + sin(angle)sin(shfZ)
        float cosa = fmaf(c95, c_cosZ[k], sinv * c_sinZ[k]);
        float x = 0.5f * (1.0f + cosa);      // in [0,1]
        x = x * x; x = x * x; x = x * x; x = x * x; x = x * x;  // ^32
        s_f1[w][idx] = x;
        float dd = s_avd[w][q] - c_shfA[k];
        s_f2[w][idx] = __expf(-8.0f * dd * dd);
    }
    WAVE_FENCE();

    // ---- phase E: angular outer-product expansion, 1056 float4 stores ----
    float4* oa = reinterpret_cast<float4*>(o + RAD);
    for (int i4 = l; i4 < ANG / 4; i4 += 64) {
        // out element e = i4*4 = q*64 + z*8 + a0
        int q  = i4 >> 4;
        int z  = (i4 >> 1) & 7;
        int a0 = (i4 & 1) * 4;
        float f1 = 2.0f * s_f1[w][q * 8 + z];
        float4 f2 = *reinterpret_cast<const float4*>(&s_f2[w][q * 8 + a0]);
        float4 v;
        v.x = f1 * f2.x;
        v.y = f1 * f2.y;
        v.z = f1 * f2.z;
        v.w = f1 * f2.w;
        oa[i4] = v;
    }
}

extern "C" void kernel_launch(void* const* d_in, const int* in_sizes, int n_in,
                              void* d_out, int out_size, void* d_ws, size_t ws_size,
                              hipStream_t stream) {
    const float* coef = (const float*)d_in[0];
    float* out = (float*)d_out;
    // 16384 atoms, 4 atoms (one per wave) per 256-thread block
    OrbitalAEVComputer_40492951667225_kernel<<<dim3(NCONF * NATOMS / ATOMS_PER_BLOCK),
                                               dim3(256), 0, stream>>>(coef, out);
}